// Round 1
// baseline (136.343 us; speedup 1.0000x reference)
//
#include <hip/hip_runtime.h>

// RWKV-4 WKV forward. B=16, T=1024, C=2048, all fp32.
// One thread per (b,c) channel; sequential over T with a depth-PF register
// prefetch ring so each wave keeps 2*PF dword loads in flight.

#define WKV_T 1024
#define WKV_PF 16   // prefetch depth (t-steps ahead)

__global__ __launch_bounds__(64, 1) void wkv_fwd_kernel(
    const float* __restrict__ w,
    const float* __restrict__ u,
    const float* __restrict__ k,
    const float* __restrict__ v,
    float* __restrict__ y,
    int T, int C)
{
    const int c = blockIdx.x * 64 + threadIdx.x;
    const int b = blockIdx.y;

    const float wc = w[c];
    const float uc = u[c];

    const size_t base = ((size_t)b * T) * C + c;
    const float* kp = k + base;
    const float* vp = v + base;
    float*       yp = y + base;

    // state: p = exp-weighted sum of v, q = normalizer, o = running log max
    float p = 0.0f, q = 0.0f, o = -1e38f;

    // prefetch ring
    float kb[WKV_PF], vb[WKV_PF];
#pragma unroll
    for (int i = 0; i < WKV_PF; ++i) {
        kb[i] = kp[(size_t)i * C];
        vb[i] = vp[(size_t)i * C];
    }

    // main loop: all iterations here have a valid prefetch target
    for (int t0 = 0; t0 < T - WKV_PF; t0 += WKV_PF) {
#pragma unroll
        for (int j = 0; j < WKV_PF; ++j) {
            const int t = t0 + j;
            const float kt = kb[j];
            const float vt = vb[j];
            // prefetch t + PF into this slot
            kb[j] = kp[(size_t)(t + WKV_PF) * C];
            vb[j] = vp[(size_t)(t + WKV_PF) * C];

            // output at time t (bonus u on current token)
            const float uk  = uc + kt;
            const float no  = fmaxf(o, uk);
            const float A   = __expf(o - no);
            const float E   = __expf(uk - no);
            const float num = A * p + E * vt;
            const float den = A * q + E;
            yp[(size_t)t * C] = __fdividef(num, den);

            // state update (decay w on history)
            const float wo  = wc + o;
            const float no2 = fmaxf(wo, kt);
            const float A2  = __expf(wo - no2);
            const float E2  = __expf(kt - no2);
            p = A2 * p + E2 * vt;
            q = A2 * q + E2;
            o = no2;
        }
    }

    // epilogue: last PF steps, no prefetch
    {
        const int t0 = T - WKV_PF;
#pragma unroll
        for (int j = 0; j < WKV_PF; ++j) {
            const int t = t0 + j;
            const float kt = kb[j];
            const float vt = vb[j];

            const float uk  = uc + kt;
            const float no  = fmaxf(o, uk);
            const float A   = __expf(o - no);
            const float E   = __expf(uk - no);
            const float num = A * p + E * vt;
            const float den = A * q + E;
            yp[(size_t)t * C] = __fdividef(num, den);

            const float wo  = wc + o;
            const float no2 = fmaxf(wo, kt);
            const float A2  = __expf(wo - no2);
            const float E2  = __expf(kt - no2);
            p = A2 * p + E2 * vt;
            q = A2 * q + E2;
            o = no2;
        }
    }
}

extern "C" void kernel_launch(void* const* d_in, const int* in_sizes, int n_in,
                              void* d_out, int out_size, void* d_ws, size_t ws_size,
                              hipStream_t stream) {
    // inputs: 0=B, 1=T, 2=C (scalars), 3=w[C], 4=u[C], 5=k[B*T*C], 6=v[B*T*C]
    const float* w = (const float*)d_in[3];
    const float* u = (const float*)d_in[4];
    const float* k = (const float*)d_in[5];
    const float* v = (const float*)d_in[6];
    float* y = (float*)d_out;

    const int C = in_sizes[3];            // 2048
    const int T = WKV_T;                  // 1024 (fixed by problem)
    const int B = in_sizes[5] / (T * C);  // 16

    dim3 grid(C / 64, B);
    dim3 block(64);
    wkv_fwd_kernel<<<grid, block, 0, stream>>>(w, u, k, v, y, T, C);
}

// Round 2
// 121.573 us; speedup vs baseline: 1.1215x; 1.1215x over previous
//
#include <hip/hip_runtime.h>

// RWKV-4 WKV forward. B=16, T=1024, C=2048, fp32.
// One thread per (b,c) channel. Double-buffered register rings (TILE=16
// t-steps each) with sched_barrier(0) pinning the batch prefetch before the
// compute phase, so 32 coalesced wave-loads stay in flight while the serial
// recurrence consumes the other ring.

#define TILE 16

__global__ __launch_bounds__(64, 1) void wkv_fwd_kernel(
    const float* __restrict__ w,
    const float* __restrict__ u,
    const float* __restrict__ kk,
    const float* __restrict__ vv,
    float* __restrict__ y,
    int T, int C)
{
    const int c = blockIdx.x * 64 + threadIdx.x;
    const int b = blockIdx.y;

    const float wc = w[c];
    const float uc = u[c];

    const size_t base = ((size_t)b * T) * C + c;
    const float* kp = kk + base;
    const float* vp = vv + base;
    float*       yp = y + base;

    // state: p = exp-weighted sum of v, q = normalizer, o = running log max
    float p = 0.0f, q = 0.0f, o = -1e38f;

    // two register rings
    float ka[TILE], va[TILE], kb[TILE], vb[TILE];

    // prologue: ring A <- t in [0, TILE)
#pragma unroll
    for (int j = 0; j < TILE; ++j) {
        ka[j] = kp[(size_t)j * C];
        va[j] = vp[(size_t)j * C];
    }

    auto step = [&](float kt, float vt, int t) {
        // output at time t (bonus u on current token)
        const float uk  = uc + kt;
        const float no  = fmaxf(o, uk);
        const float A   = __expf(o - no);
        const float E   = __expf(uk - no);
        yp[(size_t)t * C] = __fdividef(A * p + E * vt, A * q + E);
        // state update (decay w on history)
        const float wo  = wc + o;
        const float no2 = fmaxf(wo, kt);
        const float A2  = __expf(wo - no2);
        const float E2  = __expf(kt - no2);
        p = A2 * p + E2 * vt;
        q = A2 * q + E2;
        o = no2;
    };

    for (int t0 = 0; t0 < T; t0 += 2 * TILE) {
        // phase A: prefetch ring B <- [t0+TILE, t0+2*TILE)  (always in range)
#pragma unroll
        for (int j = 0; j < TILE; ++j) {
            kb[j] = kp[(size_t)(t0 + TILE + j) * C];
            vb[j] = vp[(size_t)(t0 + TILE + j) * C];
        }
        __builtin_amdgcn_sched_barrier(0);  // do not sink prefetch past compute
#pragma unroll
        for (int j = 0; j < TILE; ++j)
            step(ka[j], va[j], t0 + j);

        // phase B: prefetch ring A <- [t0+2*TILE, t0+3*TILE) if in range
        if (t0 + 2 * TILE < T) {
#pragma unroll
            for (int j = 0; j < TILE; ++j) {
                ka[j] = kp[(size_t)(t0 + 2 * TILE + j) * C];
                va[j] = vp[(size_t)(t0 + 2 * TILE + j) * C];
            }
        }
        __builtin_amdgcn_sched_barrier(0);
#pragma unroll
        for (int j = 0; j < TILE; ++j)
            step(kb[j], vb[j], t0 + TILE + j);
    }
}

extern "C" void kernel_launch(void* const* d_in, const int* in_sizes, int n_in,
                              void* d_out, int out_size, void* d_ws, size_t ws_size,
                              hipStream_t stream) {
    // inputs: 0=B, 1=T, 2=C (scalars), 3=w[C], 4=u[C], 5=k[B*T*C], 6=v[B*T*C]
    const float* w = (const float*)d_in[3];
    const float* u = (const float*)d_in[4];
    const float* k = (const float*)d_in[5];
    const float* v = (const float*)d_in[6];
    float* y = (float*)d_out;

    const int C = in_sizes[3];            // 2048
    const int T = 1024;                   // fixed by problem
    const int B = in_sizes[5] / (T * C);  // 16

    dim3 grid(C / 64, B);
    dim3 block(64);
    wkv_fwd_kernel<<<grid, block, 0, stream>>>(w, u, k, v, y, T, C);
}

// Round 3
// 103.633 us; speedup vs baseline: 1.3156x; 1.1731x over previous
//
#include <hip/hip_runtime.h>

// RWKV-4 WKV forward. B=16, T=1024, C=2048, fp32.
// One thread per (b,c). k/v staged via global_load_lds (16B/lane) into a
// 6-buffer LDS ring, 5 tiles (80 timesteps) prefetched ahead, counted
// s_waitcnt vmcnt(N) gates (T3/T4 pattern). No register rings -> no spills.

#define T_DIM 1024
#define TILE 16                  // timesteps per tile
#define NTILES (T_DIM / TILE)    // 64
#define NBUF 6                   // LDS ring depth
#define BUF_DW 2048              // 16 t * (64 k + 64 v) dwords = 8 KB

typedef const __attribute__((address_space(1))) float* gptr_t;
typedef __attribute__((address_space(3))) float* lptr_t;

__global__ __launch_bounds__(64, 1) void wkv_fwd_kernel(
    const float* __restrict__ w, const float* __restrict__ u,
    const float* __restrict__ kk, const float* __restrict__ vv,
    float* __restrict__ y, int T, int C)
{
    __shared__ __align__(16) float lds[NBUF * BUF_DW];   // 48 KB

    const int lane = threadIdx.x;
    const int c0 = blockIdx.x * 64;
    const int b  = blockIdx.y;
    const int c  = c0 + lane;

    const float wc = w[c];
    const float uc = u[c];

    const size_t cbase = (size_t)b * T * C + c0;
    // per-lane source for 16B global_load_lds: t-row (lane>>4), 4 c's at (lane&15)*4.
    // LDS linear dest [lane*16B] == [row l>>4][(l&15)*4 .. +3] == rows of 64 floats.
    const size_t lane_off = (size_t)(lane >> 4) * C + (size_t)(lane & 15) * 4;
    const float* kpf = kk + cbase + lane_off;
    const float* vpf = vv + cbase + lane_off;
    float* yq = y + cbase + lane;

    // issue one 16-t tile into buffer bi: 4 K-instrs + 4 V-instrs (8 vmcnt items)
    auto issue_tile = [&](int bi) {
        float* dst = &lds[bi * BUF_DW];
#pragma unroll
        for (int g = 0; g < 4; ++g) {
            __builtin_amdgcn_global_load_lds((gptr_t)kpf, (lptr_t)(dst + g * 512),       16, 0, 0);
            __builtin_amdgcn_global_load_lds((gptr_t)vpf, (lptr_t)(dst + g * 512 + 256), 16, 0, 0);
            kpf += 4 * C;
            vpf += 4 * C;
        }
    };

    float p = 0.f, q = 0.f, o = -1e38f;

    // prologue: tiles 0..4 in flight (40 loads)
#pragma unroll 1
    for (int n = 0; n < NBUF - 1; ++n) issue_tile(n);

#pragma unroll 1
    for (int i = 0; i < NTILES; ++i) {
        if (i + NBUF - 1 < NTILES) issue_tile((i + NBUF - 1) % NBUF);
        // vmcnt decrements in issue order. After tile i's 8 loads there are
        // >= 56 later ops (40 prefetch loads + 16 y-stores) for all i>=1,
        // so vmcnt(56) guarantees tile i landed; i==0 has only 40 later ops.
        if (i == 0) asm volatile("s_waitcnt vmcnt(40)" ::: "memory");
        else        asm volatile("s_waitcnt vmcnt(56)" ::: "memory");
        __builtin_amdgcn_sched_barrier(0);

        const float* buf = &lds[(i % NBUF) * BUF_DW];
#pragma unroll
        for (int j = 0; j < TILE; ++j) {
            const float kt = buf[(j >> 2) * 512 + (j & 3) * 64 + lane];
            const float vt = buf[(j >> 2) * 512 + 256 + (j & 3) * 64 + lane];

            // output at t: one of A/E is exactly 1 -> single exp
            const float uk = uc + kt;
            const float dd = o - uk;            // >=0 -> A=1,E=e ; <0 -> A=e,E=1
            const float e1 = __expf(-fabsf(dd));
            const float A  = dd >= 0.f ? 1.f : e1;
            const float E  = dd >= 0.f ? e1 : 1.f;
            yq[(size_t)(i * TILE + j) * C] =
                __fdividef(fmaf(A, p, E * vt), fmaf(A, q, E));

            // state update
            const float wo = wc + o;
            const float d2 = wo - kt;
            const float e2 = __expf(-fabsf(d2));
            const float A2 = d2 >= 0.f ? 1.f : e2;
            const float E2 = d2 >= 0.f ? e2 : 1.f;
            p = fmaf(A2, p, E2 * vt);
            q = fmaf(A2, q, E2);
            o = fmaxf(wo, kt);
        }
    }
}

extern "C" void kernel_launch(void* const* d_in, const int* in_sizes, int n_in,
                              void* d_out, int out_size, void* d_ws, size_t ws_size,
                              hipStream_t stream) {
    // inputs: 0=B, 1=T, 2=C (scalars), 3=w[C], 4=u[C], 5=k[B*T*C], 6=v[B*T*C]
    const float* w = (const float*)d_in[3];
    const float* u = (const float*)d_in[4];
    const float* k = (const float*)d_in[5];
    const float* v = (const float*)d_in[6];
    float* y = (float*)d_out;

    const int C = in_sizes[3];            // 2048
    const int T = T_DIM;                  // 1024 (fixed by problem)
    const int B = in_sizes[5] / (T * C);  // 16

    dim3 grid(C / 64, B);
    dim3 block(64);
    wkv_fwd_kernel<<<grid, block, 0, stream>>>(w, u, k, v, y, T, C);
}